// Round 9
// baseline (204.314 us; speedup 1.0000x reference)
//
#include <hip/hip_runtime.h>
#include <math.h>

#define BATCH 65536
#define LHIST 128
#define HFUT  32

__device__ __forceinline__ float softplusf(float x) {
    // log(1+e^x), numerically stable; matches jax.nn.softplus (uniform, runs once)
    return fmaxf(x, 0.0f) + log1pf(expf(-fabsf(x)));
}

// K ring buffer in LDS: [2 bufs][16 steps][3 comps][256 rows] floats = 96 KiB.
// row index is stride-1 across lanes -> 2 lanes/bank (free on CDNA4).
#define KSLOT(buf, st, c, row) (((((buf)*16 + (st))*3 + (c))*256) + (row))

// P/s role-split (r8, the only variant that raised VALUBusy: 34->45% at
// 2 waves/SIMD), now with the r8 overheads removed:
//  - depth-2 register prefetch of all chunk inputs, STATIC A/B parity
//    (8 straight-line segments; every LDS offset / array index is a literal)
//  - P-future dt staged under segment 7; barriers converged at top level
//  - step arithmetic byte-identical to the r8 kernel that passed.
__global__ __launch_bounds__(512, 2) void kalman_fwd(
    const float* __restrict__ v_hist,
    const float* __restrict__ dt_hist,
    const float* __restrict__ x_obs,
    const float* __restrict__ v_fut,
    const float* __restrict__ dt_fut,
    const float* __restrict__ theta,
    float* __restrict__ out)
{
    const int tid = threadIdx.x;
    const bool isP = (tid < 256);          // waves 0-3: P-role; waves 4-7: s-role
    const int row  = tid & 255;
    const int b    = blockIdx.x * 256 + row;

    __shared__ float Kls[2 * 16 * 3 * 256];   // 96 KiB -> 1 block/CU, 8 waves = 2/SIMD

    // ---- uniform parameter transforms (once per thread, wave-uniform) ----
    const float alpha = 1.0f / (1.0f + expf(-theta[0]));
    const float c     = softplusf(theta[1]);
    const float kappa = softplusf(theta[2]);
    const float vc    = softplusf(theta[3]);       // VC_MIN = 0
    const float qx    = expf(theta[4]);
    const float qu    = expf(theta[5]);
    const float Rn    = expf(theta[6]);
    const float qs    = expf(theta[7]);
    const float p0xx  = expf(theta[8]);
    const float p0uu  = expf(theta[9]);
    const float a1    = softplusf(theta[10]);
    const float d1    = softplusf(theta[11]);
    const float d2    = softplusf(theta[12]);
    const float d3    = softplusf(theta[13]);
    const float b1    = theta[14];
    const float b2    = theta[15];
    const float beta  = theta[16];
    const float rho_m = tanhf(theta[17]);
    const float qm    = expf(theta[18]);
    const float p0mm  = expf(theta[19]);
    const float vc2   = vc * vc;
    const float qxs   = qs * qx;
    const float qus   = qs * qu;
    const float rm2   = rho_m * rho_m;
    const float nal2e = -alpha * 1.44269504088896340736f;  // exp(-a*dt)=exp2(nal2e*dt)

    // ---- P-role state ----
    float p00 = p0xx, p01 = 0.0f, p02 = 0.0f, p11 = p0uu, p12 = 0.0f, p22 = p0mm;
    // ---- s-role state ----
    float sx = 0.0f, su = 0.0f, sm = 0.0f, vp1 = 0.0f, vp2 = 0.0f;

    auto P_step = [&](float dt_raw, int buf, int st) {
        float dt  = fmaxf(dt_raw, 1e-6f);
        float rho = __builtin_amdgcn_exp2f(nal2e * dt);
        float kdt = kappa * dt;
        float f0 = p00 + dt * p01;
        float f1 = p01 + dt * p11;
        float f2 = p02 + dt * p12;
        float g0 = -kdt * p00 + rho * p01 + beta * p02;
        float g1 = -kdt * p01 + rho * p11 + beta * p12;
        float g2 = -kdt * p02 + rho * p12 + beta * p22;
        float n00 = f0 + dt * f1 + qxs * dt;
        float n01 = -kdt * f0 + rho * f1 + beta * f2;
        float n02 = rho_m * f2;
        float n11 = -kdt * g0 + rho * g1 + beta * g2 + qus * dt;
        float n12 = rho_m * g2;
        float n22 = rm2 * p22 + qm;
        float S    = n00 + Rn;
        float Sinv = __builtin_amdgcn_rcpf(S);
        float K0 = n00 * Sinv, K1 = n01 * Sinv, K2 = n02 * Sinv;
        Kls[KSLOT(buf, st, 0, row)] = K0;
        Kls[KSLOT(buf, st, 1, row)] = K1;
        Kls[KSLOT(buf, st, 2, row)] = K2;
        float a = 1.0f - K0;
        p00 = a * a * n00 + Rn * K0 * K0;
        p01 = a * (n01 - K1 * n00) + Rn * K0 * K1;
        p02 = a * (n02 - K2 * n00) + Rn * K0 * K2;
        p11 = S * K1 * K1 - 2.0f * K1 * n01 + n11;
        p12 = S * K1 * K2 - K2 * n01 - K1 * n02 + n12;
        p22 = S * K2 * K2 - 2.0f * K2 * n02 + n22;
    };

    auto P_pred = [&](float dt_raw) {
        float dt  = fmaxf(dt_raw, 1e-6f);
        float rho = __builtin_amdgcn_exp2f(nal2e * dt);
        float kdt = kappa * dt;
        float f0 = p00 + dt * p01;
        float f1 = p01 + dt * p11;
        float f2 = p02 + dt * p12;
        float g0 = -kdt * p00 + rho * p01 + beta * p02;
        float g1 = -kdt * p01 + rho * p11 + beta * p12;
        float g2 = -kdt * p02 + rho * p12 + beta * p22;
        float n00 = f0 + dt * f1 + qxs * dt;
        float n01 = -kdt * f0 + rho * f1 + beta * f2;
        float n02 = rho_m * f2;
        float n11 = -kdt * g0 + rho * g1 + beta * g2 + qus * dt;
        float n12 = rho_m * g2;
        float n22 = rm2 * p22 + qm;
        p00 = n00; p01 = n01; p02 = n02; p11 = n11; p12 = n12; p22 = n22;
    };

    auto s_pred = [&](float v, float dv, float dt_raw) {
        float dt  = fmaxf(dt_raw, 1e-6f);
        float rho = __builtin_amdgcn_exp2f(nal2e * dt);
        float forcing = fmaxf(v * v - vc2, 0.0f);
        float cl = -a1 * su + b1 * v + b2 * dv
                 - d1 * su * su - d2 * su * fabsf(v) - d3 * su * fabsf(su);
        float kdt = kappa * dt;
        float x_p = sx + su * dt;
        float u_p = rho * su - kdt * sx + c * forcing * dt + cl * dt + beta * sm;
        float m_p = rho_m * sm;
        sx = x_p; su = u_p; sm = m_p;
    };

    auto s_step = [&](float vnew, float dt_raw, float y, int buf, int st) {
        float K0 = Kls[KSLOT(buf, st, 0, row)];
        float K1 = Kls[KSLOT(buf, st, 1, row)];
        float K2 = Kls[KSLOT(buf, st, 2, row)];
        s_pred(vp1, vp1 - vp2, dt_raw);
        float innov = y - sx;
        sx += K0 * innov; su += K1 * innov; sm += K2 * innov;
        vp2 = vp1; vp1 = vnew;
    };

    const float4* v4 = (const float4*)(v_hist  + (size_t)b * LHIST);
    const float4* d4 = (const float4*)(dt_hist + (size_t)b * LHIST);
    const float4* y4 = (const float4*)(x_obs   + (size_t)b * LHIST);

    auto ld16 = [&](float (&dst)[16], const float4* src, int g) {
        float4* D = (float4*)dst;
        #pragma unroll
        for (int i = 0; i < 4; ++i) D[i] = src[g * 4 + i];
    };

    auto P_cons = [&](const float (&dtc)[16], int buf) {
        #pragma unroll
        for (int st = 0; st < 16; ++st) P_step(dtc[st], buf, st);
    };
    auto s_cons = [&](const float (&vv)[16], const float (&dd)[16],
                      const float (&yy)[16], int buf) {
        #pragma unroll
        for (int st = 0; st < 16; ++st) s_step(vv[st], dd[st], yy[st], buf, st);
    };

    // ---- register staging: depth-2, static A/B parity ----
    float pA[16], pB[16];                        // P: dt chunks (even/odd)
    float sva[16], sda[16], sya[16];             // s: chunk staging A (even)
    float svb[16], sdb[16], syb[16];             // s: chunk staging B (odd)
    float fdtP[32];                              // P: future dt (staged seg 6)

    // ======================= 8 straight-line segments ======================
    // seg k: P computes chunk k (K -> buf k&1); s consumes chunk k-1.
    // Each role prefetches chunk k+2 into the buffer it just consumed.

    // --- seg 0 ---
    if (isP) {
        ld16(pA, d4, 0); ld16(pB, d4, 1);
        #pragma unroll
        for (int st = 1; st < 16; ++st) P_step(pA[st], 0, st);   // t'=1..15
        ld16(pA, d4, 2);
    } else {
        ld16(sva, v4, 0); ld16(sda, d4, 0); ld16(sya, y4, 0);
        ld16(svb, v4, 1); ld16(sdb, d4, 1); ld16(syb, y4, 1);
    }
    __syncthreads();

    // --- seg 1 ---
    if (isP) {
        P_cons(pB, 1);
        ld16(pB, d4, 3);
    } else {
        sx = sya[0]; vp1 = sva[0]; vp2 = sva[0];                 // t'=0 init
        #pragma unroll
        for (int st = 1; st < 16; ++st) s_step(sva[st], sda[st], sya[st], 0, st);
        ld16(sva, v4, 2); ld16(sda, d4, 2); ld16(sya, y4, 2);
    }
    __syncthreads();

    // --- seg 2 ---
    if (isP) { P_cons(pA, 0); ld16(pA, d4, 4); }
    else     { s_cons(svb, sdb, syb, 1);
               ld16(svb, v4, 3); ld16(sdb, d4, 3); ld16(syb, y4, 3); }
    __syncthreads();

    // --- seg 3 ---
    if (isP) { P_cons(pB, 1); ld16(pB, d4, 5); }
    else     { s_cons(sva, sda, sya, 0);
               ld16(sva, v4, 4); ld16(sda, d4, 4); ld16(sya, y4, 4); }
    __syncthreads();

    // --- seg 4 ---
    if (isP) { P_cons(pA, 0); ld16(pA, d4, 6); }
    else     { s_cons(svb, sdb, syb, 1);
               ld16(svb, v4, 5); ld16(sdb, d4, 5); ld16(syb, y4, 5); }
    __syncthreads();

    // --- seg 5 ---
    if (isP) { P_cons(pB, 1); ld16(pB, d4, 7); }
    else     { s_cons(sva, sda, sya, 0);
               ld16(sva, v4, 6); ld16(sda, d4, 6); ld16(sya, y4, 6); }
    __syncthreads();

    // --- seg 6: P stages its future dt under this chunk ---
    if (isP) {
        P_cons(pA, 0);
        float4* FD = (float4*)fdtP;
        const float4* df4 = (const float4*)(dt_fut + (size_t)b * HFUT);
        #pragma unroll
        for (int i = 0; i < 8; ++i) FD[i] = df4[i];
    } else {
        s_cons(svb, sdb, syb, 1);
        ld16(svb, v4, 7); ld16(sdb, d4, 7); ld16(syb, y4, 7);
    }
    __syncthreads();

    // --- seg 7 ---
    if (isP) { P_cons(pB, 1); }
    else     { s_cons(sva, sda, sya, 0); }
    __syncthreads();

    // ===================== epilogue: roles fully independent ================
    if (isP) {
        float oxv[32];
        #pragma unroll
        for (int j = 0; j < HFUT; ++j) { P_pred(fdtP[j]); oxv[j] = p00; }
        float4* xv = (float4*)(out + (size_t)BATCH * HFUT + (size_t)b * HFUT);
        float4* OXV = (float4*)oxv;
        #pragma unroll
        for (int i = 0; i < 8; ++i) xv[i] = OXV[i];
    } else {
        s_cons(svb, sdb, syb, 1);                 // chunk 7 (published at seg-7 bar)
        // future inputs (history staging regs are dead now)
        float fv[32], fdt[32];
        float4* FV = (float4*)fv; float4* FD = (float4*)fdt;
        const float4* vf4 = (const float4*)(v_fut  + (size_t)b * HFUT);
        const float4* df4 = (const float4*)(dt_fut + (size_t)b * HFUT);
        #pragma unroll
        for (int i = 0; i < 8; ++i) { FV[i] = vf4[i]; FD[i] = df4[i]; }
        float oxp[32], oue[32];
        float vp = vp1;
        #pragma unroll
        for (int j = 0; j < HFUT; ++j) {
            s_pred(fv[j], fv[j] - vp, fdt[j]);
            vp = fv[j];
            oxp[j] = sx; oue[j] = su;
        }
        float4* xp = (float4*)(out + (size_t)b * HFUT);
        float4* ue = (float4*)(out + 2 * (size_t)BATCH * HFUT + (size_t)b * HFUT);
        float4* OXP = (float4*)oxp; float4* OUE = (float4*)oue;
        #pragma unroll
        for (int i = 0; i < 8; ++i) { xp[i] = OXP[i]; ue[i] = OUE[i]; }
    }
}

extern "C" void kernel_launch(void* const* d_in, const int* in_sizes, int n_in,
                              void* d_out, int out_size, void* d_ws, size_t ws_size,
                              hipStream_t stream) {
    const float* v_hist  = (const float*)d_in[0];
    const float* dt_hist = (const float*)d_in[1];
    const float* x_obs   = (const float*)d_in[2];
    const float* v_fut   = (const float*)d_in[3];
    const float* dt_fut  = (const float*)d_in[4];
    const float* theta   = (const float*)d_in[5];
    float* out = (float*)d_out;

    // 256 blocks x 512 threads: 2 threads per batch row -> 2048 waves
    // = 2 waves/SIMD (the only occupancy unlock available at fixed BATCH).
    dim3 grid(BATCH / 256), block(512);
    hipLaunchKernelGGL(kalman_fwd, grid, block, 0, stream,
                       v_hist, dt_hist, x_obs, v_fut, dt_fut, theta, out);
}

// Round 10
// 171.930 us; speedup vs baseline: 1.1884x; 1.1884x over previous
//
#include <hip/hip_runtime.h>
#include <math.h>

#define BATCH 65536
#define LHIST 128
#define HFUT  32
#define NR    64            // batch rows per block (wave0 = P-role, wave1 = s-role)

__device__ __forceinline__ float softplusf(float x) {
    // log(1+e^x), numerically stable; matches jax.nn.softplus (uniform, runs once)
    return fmaxf(x, 0.0f) + log1pf(expf(-fabsf(x)));
}

// K ring: [2 bufs][8 steps][5 comps: K0,K1,K2,dt,rho][64 rows] = 20 KiB/block.
// lane->row stride-1: 2 lanes/bank, conflict-free on CDNA4.
#define RS(buf, st, c) ((((buf)*8 + (st))*5 + (c))*NR)

// r8 proved the P/s role split is the only lever that moved VALUBusy (34->45%)
// at the structurally-fixed 2 waves/SIMD. r9 proved (again) that >50 floats of
// live-across-barrier register staging spills. This version keeps r8's verified
// arithmetic and removes its stalls within those laws:
//  - 1024 small blocks (64 rows, 2 waves): 4 INDEPENDENT blocks/CU, so barrier
//    lockstep no longer synchronizes stalls -- another block's wave fills gaps.
//  - CH=8 depth-1 prefetch, static A/B parity: s stages v,y (32 regs), P stages
//    dt (16 regs); every load covered by ~1 segment of compute.
//  - dt,rho ride the K-ring: s never reads dt_hist (no dup fetch, -6 inst/step).
__global__ __launch_bounds__(128, 2) void kalman_fwd(
    const float* __restrict__ v_hist,
    const float* __restrict__ dt_hist,
    const float* __restrict__ x_obs,
    const float* __restrict__ v_fut,
    const float* __restrict__ dt_fut,
    const float* __restrict__ theta,
    float* __restrict__ out)
{
    const int tid  = threadIdx.x;
    const int lane = tid & 63;
    const bool isP = (tid < 64);
    const int b    = blockIdx.x * NR + lane;

    __shared__ float ring[2 * 8 * 5 * NR];     // 20 KiB

    // ---- uniform parameter transforms (once per thread, wave-uniform) ----
    const float alpha = 1.0f / (1.0f + expf(-theta[0]));
    const float c     = softplusf(theta[1]);
    const float kappa = softplusf(theta[2]);
    const float vc    = softplusf(theta[3]);       // VC_MIN = 0
    const float qx    = expf(theta[4]);
    const float qu    = expf(theta[5]);
    const float Rn    = expf(theta[6]);
    const float qs    = expf(theta[7]);
    const float p0xx  = expf(theta[8]);
    const float p0uu  = expf(theta[9]);
    const float a1    = softplusf(theta[10]);
    const float d1    = softplusf(theta[11]);
    const float d2    = softplusf(theta[12]);
    const float d3    = softplusf(theta[13]);
    const float b1    = theta[14];
    const float b2    = theta[15];
    const float beta  = theta[16];
    const float rho_m = tanhf(theta[17]);
    const float qm    = expf(theta[18]);
    const float p0mm  = expf(theta[19]);
    const float vc2   = vc * vc;
    const float qxs   = qs * qx;
    const float qus   = qs * qu;
    const float rm2   = rho_m * rho_m;
    const float nal2e = -alpha * 1.44269504088896340736f;  // exp(-a*dt)=exp2(nal2e*dt)

    // ---- P-role state ----
    float p00 = p0xx, p01 = 0.0f, p02 = 0.0f, p11 = p0uu, p12 = 0.0f, p22 = p0mm;
    // ---- s-role state ----
    float sx = 0.0f, su = 0.0f, sm = 0.0f, vp1 = 0.0f, vp2 = 0.0f;

    // P: one history step. Writes K0,K1,K2,dt,rho to ring slot (buf,st).
    auto P_step = [&](float dt_raw, int buf, int st) {
        float dt  = fmaxf(dt_raw, 1e-6f);
        float rho = __builtin_amdgcn_exp2f(nal2e * dt);
        float kdt = kappa * dt;
        float f0 = p00 + dt * p01;
        float f1 = p01 + dt * p11;
        float f2 = p02 + dt * p12;
        float g0 = -kdt * p00 + rho * p01 + beta * p02;
        float g1 = -kdt * p01 + rho * p11 + beta * p12;
        float g2 = -kdt * p02 + rho * p12 + beta * p22;
        float n00 = f0 + dt * f1 + qxs * dt;
        float n01 = -kdt * f0 + rho * f1 + beta * f2;
        float n02 = rho_m * f2;
        float n11 = -kdt * g0 + rho * g1 + beta * g2 + qus * dt;
        float n12 = rho_m * g2;
        float n22 = rm2 * p22 + qm;
        float S    = n00 + Rn;
        float Sinv = __builtin_amdgcn_rcpf(S);
        float K0 = n00 * Sinv, K1 = n01 * Sinv, K2 = n02 * Sinv;
        ring[RS(buf, st, 0) + lane] = K0;
        ring[RS(buf, st, 1) + lane] = K1;
        ring[RS(buf, st, 2) + lane] = K2;
        ring[RS(buf, st, 3) + lane] = dt;
        ring[RS(buf, st, 4) + lane] = rho;
        float a = 1.0f - K0;
        p00 = a * a * n00 + Rn * K0 * K0;
        p01 = a * (n01 - K1 * n00) + Rn * K0 * K1;
        p02 = a * (n02 - K2 * n00) + Rn * K0 * K2;
        p11 = S * K1 * K1 - 2.0f * K1 * n01 + n11;
        p12 = S * K1 * K2 - K2 * n01 - K1 * n02 + n12;
        p22 = S * K2 * K2 - 2.0f * K2 * n02 + n22;
    };

    // P: predict-only (future rollout)
    auto P_pred = [&](float dt_raw) {
        float dt  = fmaxf(dt_raw, 1e-6f);
        float rho = __builtin_amdgcn_exp2f(nal2e * dt);
        float kdt = kappa * dt;
        float f0 = p00 + dt * p01;
        float f1 = p01 + dt * p11;
        float f2 = p02 + dt * p12;
        float g0 = -kdt * p00 + rho * p01 + beta * p02;
        float g1 = -kdt * p01 + rho * p11 + beta * p12;
        float g2 = -kdt * p02 + rho * p12 + beta * p22;
        float n00 = f0 + dt * f1 + qxs * dt;
        float n01 = -kdt * f0 + rho * f1 + beta * f2;
        float n02 = rho_m * f2;
        float n11 = -kdt * g0 + rho * g1 + beta * g2 + qus * dt;
        float n12 = rho_m * g2;
        float n22 = rm2 * p22 + qm;
        p00 = n00; p01 = n01; p02 = n02; p11 = n11; p12 = n12; p22 = n22;
    };

    // s: one history step. dt,rho come from the ring (bit-identical to local).
    auto s_step = [&](float vnew, float y, int buf, int st) {
        float K0  = ring[RS(buf, st, 0) + lane];
        float K1  = ring[RS(buf, st, 1) + lane];
        float K2  = ring[RS(buf, st, 2) + lane];
        float dt  = ring[RS(buf, st, 3) + lane];
        float rho = ring[RS(buf, st, 4) + lane];
        float v = vp1, dv = vp1 - vp2;
        float forcing = fmaxf(v * v - vc2, 0.0f);
        float cl = -a1 * su + b1 * v + b2 * dv
                 - d1 * su * su - d2 * su * fabsf(v) - d3 * su * fabsf(su);
        float x_p = sx + su * dt;
        float u_p = rho * su - (kappa * dt) * sx + c * forcing * dt + cl * dt + beta * sm;
        float m_p = rho_m * sm;
        sx = x_p; su = u_p; sm = m_p;
        float innov = y - sx;
        sx += K0 * innov; su += K1 * innov; sm += K2 * innov;
        vp2 = vp1; vp1 = vnew;
    };

    // s: full predict (future rollout; computes its own dt/rho)
    auto s_pred = [&](float v, float dv, float dt_raw) {
        float dt  = fmaxf(dt_raw, 1e-6f);
        float rho = __builtin_amdgcn_exp2f(nal2e * dt);
        float forcing = fmaxf(v * v - vc2, 0.0f);
        float cl = -a1 * su + b1 * v + b2 * dv
                 - d1 * su * su - d2 * su * fabsf(v) - d3 * su * fabsf(su);
        float kdt = kappa * dt;
        float x_p = sx + su * dt;
        float u_p = rho * su - kdt * sx + c * forcing * dt + cl * dt + beta * sm;
        float m_p = rho_m * sm;
        sx = x_p; su = u_p; sm = m_p;
    };

    const float4* v4 = (const float4*)(v_hist  + (size_t)b * LHIST);
    const float4* d4 = (const float4*)(dt_hist + (size_t)b * LHIST);
    const float4* y4 = (const float4*)(x_obs   + (size_t)b * LHIST);

    auto ld8 = [&](float (&dst)[8], const float4* src, int chunk) {
        float4* D = (float4*)dst;
        D[0] = src[chunk * 2]; D[1] = src[chunk * 2 + 1];
    };

    // ---- staging (the spill law: 48 floats total, static A/B parity) ----
    float dtA[8], dtB[8];                 // P role
    float vA[8], yA[8], vB[8], yB[8];     // s role

    if (isP) { ld8(dtA, d4, 0); ld8(dtB, d4, 1); }
    else     { ld8(vA, v4, 0); ld8(yA, y4, 0); ld8(vB, v4, 1); ld8(yB, y4, 1); }

    // ---- seg 0: P computes chunk 0 (t'=1..7); s only loads ----
    if (isP) {
        #pragma unroll
        for (int st = 1; st < 8; ++st) P_step(dtA[st], 0, st);
        ld8(dtA, d4, 2);
    }
    __syncthreads();

    // ---- segs 1..14 as 7 pairs; chunk k -> ring buf k&1; s lags P by 1 ----
    #pragma unroll 1
    for (int it = 0; it < 7; ++it) {
        // segE: P chunk 2it+1 (buf1); s consumes chunk 2it (buf0) from A regs
        if (isP) {
            #pragma unroll
            for (int st = 0; st < 8; ++st) P_step(dtB[st], 1, st);
            ld8(dtB, d4, 2 * it + 3);
        } else {
            if (it == 0) {
                sx = yA[0]; vp1 = vA[0]; vp2 = vA[0];        // t'=0 init
                #pragma unroll
                for (int st = 1; st < 8; ++st) s_step(vA[st], yA[st], 0, st);
            } else {
                #pragma unroll
                for (int st = 0; st < 8; ++st) s_step(vA[st], yA[st], 0, st);
            }
            ld8(vA, v4, 2 * it + 2); ld8(yA, y4, 2 * it + 2);
        }
        __syncthreads();
        // segO: P chunk 2it+2 (buf0); s consumes chunk 2it+1 (buf1) from B regs
        if (isP) {
            #pragma unroll
            for (int st = 0; st < 8; ++st) P_step(dtA[st], 0, st);
            int nc = 2 * it + 4; nc = (nc > 15) ? 15 : nc;   // it=6: harmless reload
            ld8(dtA, d4, nc);
        } else {
            #pragma unroll
            for (int st = 0; st < 8; ++st) s_step(vB[st], yB[st], 1, st);
            ld8(vB, v4, 2 * it + 3); ld8(yB, y4, 2 * it + 3);
        }
        __syncthreads();
    }

    // ---- seg 15: P computes chunk 15 (buf1) + stages future dt; s: chunk 14 --
    float fdtP[32];
    if (isP) {
        #pragma unroll
        for (int st = 0; st < 8; ++st) P_step(dtB[st], 1, st);
        float4* FD = (float4*)fdtP;
        const float4* df4 = (const float4*)(dt_fut + (size_t)b * HFUT);
        #pragma unroll
        for (int i = 0; i < 8; ++i) FD[i] = df4[i];
    } else {
        #pragma unroll
        for (int st = 0; st < 8; ++st) s_step(vA[st], yA[st], 0, st);
    }
    __syncthreads();

    // ---- epilogue: roles fully independent ----
    if (isP) {
        float oxv[32];
        #pragma unroll
        for (int j = 0; j < HFUT; ++j) { P_pred(fdtP[j]); oxv[j] = p00; }
        float4* xv = (float4*)(out + (size_t)BATCH * HFUT + (size_t)b * HFUT);
        float4* OXV = (float4*)oxv;
        #pragma unroll
        for (int i = 0; i < 8; ++i) xv[i] = OXV[i];
    } else {
        // s consumes chunk 15 (ring buf1, published at the last barrier)
        #pragma unroll
        for (int st = 0; st < 8; ++st) s_step(vB[st], yB[st], 1, st);
        // vp1 = v_hist[b][127]
        float fv[32], fdt[32];
        float4* FV = (float4*)fv; float4* FD = (float4*)fdt;
        const float4* vf4 = (const float4*)(v_fut  + (size_t)b * HFUT);
        const float4* df4 = (const float4*)(dt_fut + (size_t)b * HFUT);
        #pragma unroll
        for (int i = 0; i < 8; ++i) { FV[i] = vf4[i]; FD[i] = df4[i]; }
        float oxp[32], oue[32];
        float vp = vp1;
        #pragma unroll
        for (int j = 0; j < HFUT; ++j) {
            s_pred(fv[j], fv[j] - vp, fdt[j]);
            vp = fv[j];
            oxp[j] = sx; oue[j] = su;
        }
        float4* xp = (float4*)(out + (size_t)b * HFUT);
        float4* ue = (float4*)(out + 2 * (size_t)BATCH * HFUT + (size_t)b * HFUT);
        float4* OXP = (float4*)oxp; float4* OUE = (float4*)oue;
        #pragma unroll
        for (int i = 0; i < 8; ++i) { xp[i] = OXP[i]; ue[i] = OUE[i]; }
    }
}

extern "C" void kernel_launch(void* const* d_in, const int* in_sizes, int n_in,
                              void* d_out, int out_size, void* d_ws, size_t ws_size,
                              hipStream_t stream) {
    const float* v_hist  = (const float*)d_in[0];
    const float* dt_hist = (const float*)d_in[1];
    const float* x_obs   = (const float*)d_in[2];
    const float* v_fut   = (const float*)d_in[3];
    const float* dt_fut  = (const float*)d_in[4];
    const float* theta   = (const float*)d_in[5];
    float* out = (float*)d_out;

    // 1024 blocks x 128 threads (64 rows, wave0=P / wave1=s):
    // 4 independent barrier groups per CU -> stalls de-synchronized.
    dim3 grid(BATCH / NR), block(128);
    hipLaunchKernelGGL(kalman_fwd, grid, block, 0, stream,
                       v_hist, dt_hist, x_obs, v_fut, dt_fut, theta, out);
}